// Round 9
// baseline (337.468 us; speedup 1.0000x reference)
//
#include <hip/hip_runtime.h>
#include <hip/hip_bf16.h>

// SocialGNN: 2-layer GCN, N=100000 nodes, E=1600000 edges (+ self loops),
// feat 256 -> 128 (relu) -> 16.
//
// R18 = R16 (335us, best) + src-half split inside each CSR row: k_sortb's
// counting-sort key becomes (dst&127)*2 + (src>=n/2), so every node's edge
// list is low-src-half first, high-half second. All waves sweep rows
// front-to-back at similar rates -> the instantaneous gather working set
// halves (25.6 -> ~12.8 MB) -> higher L2 hit rate, fewer L2-miss bytes.
// agg1 itself is byte-identical to R16 (edge reordering within a row is
// already tolerated: LDS-atomic race order). R17 fusion REVERTED: epilogue
// VGPR 24->64 + serial shfl tree collapsed occupancy 70->38% (90us > 61+8).
// History: R2 -- never funnel E atomics into <1K addresses. R4 -- bf16
// intermediates halve gather traffic. R7 -- per-wave-redundant MFMA operand
// streams = 2x regression. R9 -- resident-B LDS gemm1. R10-R13 -- XCD
// feature-chunking abandoned (reordering NODES poisons store coalescing;
// reordering EDGES within a row is free). R14 -- 8-deep agg1 61us, traffic
// as predicted. R16 -- gemm1 half-K LDS 5 blk/CU, agg2 divergent 8-deep, nt
// hints: 343->335us.

typedef __attribute__((ext_vector_type(8))) short short8;
typedef __attribute__((ext_vector_type(4))) float f32x4;
typedef __attribute__((ext_vector_type(2))) unsigned int u32x2;
typedef __attribute__((ext_vector_type(4))) unsigned int u32x4;

__device__ inline unsigned short f2bf(float f) {
    __hip_bfloat16 h = __float2bfloat16(f);
    return *(unsigned short*)&h;
}
__device__ inline float bf2f(unsigned short u) {
    unsigned int v = ((unsigned int)u) << 16;
    return *(float*)&v;
}

#define N_FEAT_IN 256
#define NBUCK 1024     // dst>>7; used buckets = ceil(n/128) = 782
#define NBINBLK 256    // partition blocks; bbc is [NBUCK][NBINBLK]

// ---------------- partition pass 1: per-(block,bucket) LDS histogram ----------------
__global__ __launch_bounds__(256) void k_bhist(const int* __restrict__ dst,
                                               int* __restrict__ bbc, int E, int chunk) {
    __shared__ int lcnt[NBUCK];
    for (int i = threadIdx.x; i < NBUCK; i += 256) lcnt[i] = 0;
    __syncthreads();
    int start = blockIdx.x * chunk;
    int end = min(start + chunk, E);
    for (int e = start + threadIdx.x; e < end; e += 256)
        atomicAdd(&lcnt[dst[e] >> 7], 1);
    __syncthreads();
    for (int i = threadIdx.x; i < NBUCK; i += 256)
        bbc[i * NBINBLK + blockIdx.x] = lcnt[i];
}

// ---- partition pass 2: per-bucket local exclusive scan across blocks + totals ----
__global__ __launch_bounds__(256) void k_bexscan(int* __restrict__ bbc,
                                                 int* __restrict__ btot) {
    __shared__ int ts[NBINBLK];
    int bucket = blockIdx.x;
    int t = threadIdx.x;
    int v = bbc[bucket * NBINBLK + t];
    ts[t] = v; __syncthreads();
    for (int off = 1; off < NBINBLK; off <<= 1) {
        int x = (t >= off) ? ts[t - off] : 0;
        __syncthreads();
        ts[t] += x;
        __syncthreads();
    }
    bbc[bucket * NBINBLK + t] = ts[t] - v;   // local exclusive (no base yet)
    if (t == NBINBLK - 1) btot[bucket] = ts[t];
}

// ---------------- bucket-total exclusive scan -> bucket bases ----------------
__global__ __launch_bounds__(1024) void k_bscan(const int* __restrict__ btot,
                                                int* __restrict__ bbase) {
    __shared__ int ts[NBUCK];
    int t = threadIdx.x;
    int v = btot[t];
    ts[t] = v; __syncthreads();
    for (int off = 1; off < NBUCK; off <<= 1) {
        int x = (t >= off) ? ts[t - off] : 0;
        __syncthreads();
        ts[t] += x;
        __syncthreads();
    }
    bbase[t] = ts[t] - v;  // exclusive
}

// ---------------- partition pass 3: binned write (24-bit packed) ----------------
// packed edge: bits 0-16 src (n<2^17), bits 17-23 dst&127.
__global__ __launch_bounds__(256) void k_bin2(const int* __restrict__ src,
                                              const int* __restrict__ dst,
                                              const int* __restrict__ bbc,
                                              const int* __restrict__ bbase,
                                              int* __restrict__ ebuf, int E, int chunk) {
    __shared__ int lcur[NBUCK];
    for (int i = threadIdx.x; i < NBUCK; i += 256)
        lcur[i] = bbc[i * NBINBLK + blockIdx.x] + bbase[i];
    __syncthreads();
    int start = blockIdx.x * chunk;
    int end = min(start + chunk, E);
    for (int e = start + threadIdx.x; e < end; e += 256) {
        int s = src[e], d = dst[e];
        int pos = atomicAdd(&lcur[d >> 7], 1);  // LDS atomic
        ebuf[pos] = s | ((d & 127) << 17);
    }
}

// ---- per-bucket counting sort: ebuf window -> csr; also row_ptr, dinv ----
// R18: 256 bins -- key = (dst&127)*2 + (src>=n/2). Each row's edges land
// low-src-half first, then high-half, halving agg1's instantaneous gather
// working set. Edge order within a row is already arbitrary (atomic races).
__global__ __launch_bounds__(256) void k_sortb(const int* __restrict__ ebuf,
                                               const int* __restrict__ bbase,
                                               int* __restrict__ row_ptr,
                                               float* __restrict__ dinv,
                                               int* __restrict__ csr, int n, int E) {
    __shared__ int lcnt[256];
    __shared__ int lcur[256];
    int b = blockIdx.x;
    int node0 = b << 7;
    int nodes = min(128, n - node0);
    int t = threadIdx.x;
    int s_start = bbase[b];
    int s_end = bbase[b + 1];
    const int half = n >> 1;
    lcnt[t] = 0;
    __syncthreads();
    for (int e = s_start + t; e < s_end; e += 256) {
        int p = ebuf[e];
        int key = (((p >> 17) & 127) << 1) | ((p & 0x1FFFF) >= half ? 1 : 0);
        atomicAdd(&lcnt[key], 1);
    }
    __syncthreads();
    int v = lcnt[t];
    lcur[t] = v;
    __syncthreads();
    for (int off = 1; off < 256; off <<= 1) {
        int x = (t >= off) ? lcur[t - off] : 0;
        __syncthreads();
        lcur[t] += x;
        __syncthreads();
    }
    int excl = lcur[t] - v;                  // exclusive prefix of key t
    __syncthreads();
    lcur[t] = s_start + excl;                // write cursor per key
    __syncthreads();
    if (t < nodes) {
        int start = lcur[2 * t];
        int next = (t == 127) ? s_end : lcur[2 * t + 2];
        row_ptr[node0 + t] = start;
        dinv[node0 + t] = rsqrtf((float)(next - start) + 1.0f);  // +1 self-loop
    }
    if (b == 0 && t == 0) row_ptr[n] = E;
    __syncthreads();                          // cursor reads done before scatter
    for (int e = s_start + t; e < s_end; e += 256) {
        int p = ebuf[e];
        int s = p & 0x1FFFF;
        int key = (((p >> 17) & 127) << 1) | (s >= half ? 1 : 0);
        int pos = atomicAdd(&lcur[key], 1);  // LDS atomic
        csr[pos] = s;
    }
}

// ------ W1 [256][128] f32 -> W1t packed [kq 0..31][n 0..127][j 0..7] bf16 ------
// element (n, k=kq*8+j) lives at W1t[kq*1024 + n*8 + j].
__global__ void k_prep(const float* __restrict__ W1, unsigned short* __restrict__ W1t) {
    int nn = blockIdx.x;          // 0..127
    int k = threadIdx.x;          // 0..255
    int kq = k >> 3, j = k & 7;
    W1t[kq * 1024 + nn * 8 + j] = f2bf(W1[k * 128 + nn]);
}

// ---------------- GEMM1 (MFMA, half-K resident-B): X[M,256]f32 @ W1 -> h1s ----------
// 32 KB LDS (half of W1 at a time), 2 compute phases, 3 barriers/block ->
// 5 blocks/CU. X loads non-temporal (read-once stream).
__global__ __launch_bounds__(256) void k_gemm1(const float* __restrict__ X,
                                               const unsigned short* __restrict__ W1t,
                                               const float* __restrict__ dinv,
                                               unsigned short* __restrict__ h1s, int M) {
    __shared__ unsigned short Bs[16384];   // 32 KB, [kq' 0..15][n][8]
    const int tid = threadIdx.x;
    const int wv = tid >> 6;
    const int lane = tid & 63;
    const int hq = lane >> 4;       // quad 0..3
    const int l15 = lane & 15;
    const int block_row = blockIdx.x * 64;

    int arow = block_row + wv * 16 + l15;
    if (arow >= M) arow = M - 1;                       // clamp; stores masked
    const float* xp = X + (size_t)arow * 256 + hq * 8;

    f32x4 acc[8];
#pragma unroll
    for (int c = 0; c < 8; ++c) acc[c] = (f32x4){0.f, 0.f, 0.f, 0.f};

#pragma unroll
    for (int ph = 0; ph < 2; ++ph) {
        if (ph) __syncthreads();           // all reads of phase 0 done
#pragma unroll
        for (int i = 0; i < 8; ++i)
            ((u32x4*)Bs)[tid + i * 256] = ((const u32x4*)W1t)[ph * 2048 + tid + i * 256];
        __syncthreads();
#pragma unroll
        for (int ks4 = 0; ks4 < 4; ++ks4) {            // ks = ph*4 + ks4
            const int ks = ph * 4 + ks4;
            f32x4 a0 = __builtin_nontemporal_load((const f32x4*)(xp + 32 * ks));
            f32x4 a1 = __builtin_nontemporal_load((const f32x4*)(xp + 32 * ks + 4));
            short8 a;
            a[0] = (short)f2bf(a0[0]); a[1] = (short)f2bf(a0[1]);
            a[2] = (short)f2bf(a0[2]); a[3] = (short)f2bf(a0[3]);
            a[4] = (short)f2bf(a1[0]); a[5] = (short)f2bf(a1[1]);
            a[6] = (short)f2bf(a1[2]); a[7] = (short)f2bf(a1[3]);
            const unsigned short* bp = Bs + (ks4 * 4 + hq) * 1024 + l15 * 8;
#pragma unroll
            for (int c = 0; c < 8; ++c) {
                short8 b = *(const short8*)(bp + c * 128);
                acc[c] = __builtin_amdgcn_mfma_f32_16x16x32_bf16(a, b, acc[c], 0, 0, 0);
            }
        }
    }
    // D: row = 16wv + hq*4 + r, col = c*16 + l15
#pragma unroll
    for (int r = 0; r < 4; ++r) {
        int row = block_row + 16 * wv + hq * 4 + r;
        if (row < M) {
            float dv = dinv[row];
#pragma unroll
            for (int c = 0; c < 8; ++c) {
                int col = c * 16 + l15;
                h1s[(size_t)row * 128 + col] = f2bf(acc[c][r] * dv);
            }
        }
    }
}

// ---------------- agg1: TWO nodes per wave (32 lanes x uint2 = 256B row) -------------
// R14 structure (proven 61us, 188MB fetch). tbuf store non-temporal.
__global__ __launch_bounds__(256) void k_agg1(const unsigned short* __restrict__ h1s,
                                              const int* __restrict__ rp,
                                              const int* __restrict__ csr,
                                              const float* __restrict__ dinv,
                                              const float* __restrict__ b1,
                                              unsigned short* __restrict__ tbuf, int n) {
    int pr = (blockIdx.x * 256 + threadIdx.x) >> 6;  // wave id = node pair
    int lane = threadIdx.x & 63;
    int half = lane >> 5;
    int l = lane & 31;
    int node = pr * 2 + half;
    if (node >= n) return;
    const uint2* hv = (const uint2*)h1s;  // 32 uint2 per 128-feat row
    uint2 us = hv[((unsigned)node << 5) + l];  // self (already *dinv)
    float a0 = bf2f((unsigned short)(us.x & 0xffff));
    float a1 = bf2f((unsigned short)(us.x >> 16));
    float a2 = bf2f((unsigned short)(us.y & 0xffff));
    float a3 = bf2f((unsigned short)(us.y >> 16));
    int start = rp[node], end = rp[node + 1];
    int e = start;
    for (; e + 8 <= end; e += 8) {
        uint2 u0 = hv[((unsigned)csr[e + 0] << 5) + l];
        uint2 u1 = hv[((unsigned)csr[e + 1] << 5) + l];
        uint2 u2 = hv[((unsigned)csr[e + 2] << 5) + l];
        uint2 u3 = hv[((unsigned)csr[e + 3] << 5) + l];
        uint2 u4 = hv[((unsigned)csr[e + 4] << 5) + l];
        uint2 u5 = hv[((unsigned)csr[e + 5] << 5) + l];
        uint2 u6 = hv[((unsigned)csr[e + 6] << 5) + l];
        uint2 u7 = hv[((unsigned)csr[e + 7] << 5) + l];
        a0 += (bf2f((unsigned short)(u0.x & 0xffff)) + bf2f((unsigned short)(u1.x & 0xffff))) +
              (bf2f((unsigned short)(u2.x & 0xffff)) + bf2f((unsigned short)(u3.x & 0xffff))) +
              (bf2f((unsigned short)(u4.x & 0xffff)) + bf2f((unsigned short)(u5.x & 0xffff))) +
              (bf2f((unsigned short)(u6.x & 0xffff)) + bf2f((unsigned short)(u7.x & 0xffff)));
        a1 += (bf2f((unsigned short)(u0.x >> 16)) + bf2f((unsigned short)(u1.x >> 16))) +
              (bf2f((unsigned short)(u2.x >> 16)) + bf2f((unsigned short)(u3.x >> 16))) +
              (bf2f((unsigned short)(u4.x >> 16)) + bf2f((unsigned short)(u5.x >> 16))) +
              (bf2f((unsigned short)(u6.x >> 16)) + bf2f((unsigned short)(u7.x >> 16)));
        a2 += (bf2f((unsigned short)(u0.y & 0xffff)) + bf2f((unsigned short)(u1.y & 0xffff))) +
              (bf2f((unsigned short)(u2.y & 0xffff)) + bf2f((unsigned short)(u3.y & 0xffff))) +
              (bf2f((unsigned short)(u4.y & 0xffff)) + bf2f((unsigned short)(u5.y & 0xffff))) +
              (bf2f((unsigned short)(u6.y & 0xffff)) + bf2f((unsigned short)(u7.y & 0xffff)));
        a3 += (bf2f((unsigned short)(u0.y >> 16)) + bf2f((unsigned short)(u1.y >> 16))) +
              (bf2f((unsigned short)(u2.y >> 16)) + bf2f((unsigned short)(u3.y >> 16))) +
              (bf2f((unsigned short)(u4.y >> 16)) + bf2f((unsigned short)(u5.y >> 16))) +
              (bf2f((unsigned short)(u6.y >> 16)) + bf2f((unsigned short)(u7.y >> 16)));
    }
    for (; e + 4 <= end; e += 4) {
        uint2 u0 = hv[((unsigned)csr[e + 0] << 5) + l];
        uint2 u1 = hv[((unsigned)csr[e + 1] << 5) + l];
        uint2 u2 = hv[((unsigned)csr[e + 2] << 5) + l];
        uint2 u3 = hv[((unsigned)csr[e + 3] << 5) + l];
        a0 += (bf2f((unsigned short)(u0.x & 0xffff)) + bf2f((unsigned short)(u1.x & 0xffff))) +
              (bf2f((unsigned short)(u2.x & 0xffff)) + bf2f((unsigned short)(u3.x & 0xffff)));
        a1 += (bf2f((unsigned short)(u0.x >> 16)) + bf2f((unsigned short)(u1.x >> 16))) +
              (bf2f((unsigned short)(u2.x >> 16)) + bf2f((unsigned short)(u3.x >> 16)));
        a2 += (bf2f((unsigned short)(u0.y & 0xffff)) + bf2f((unsigned short)(u1.y & 0xffff))) +
              (bf2f((unsigned short)(u2.y & 0xffff)) + bf2f((unsigned short)(u3.y & 0xffff)));
        a3 += (bf2f((unsigned short)(u0.y >> 16)) + bf2f((unsigned short)(u1.y >> 16))) +
              (bf2f((unsigned short)(u2.y >> 16)) + bf2f((unsigned short)(u3.y >> 16)));
    }
    for (; e < end; ++e) {
        uint2 u = hv[((unsigned)csr[e] << 5) + l];
        a0 += bf2f((unsigned short)(u.x & 0xffff));
        a1 += bf2f((unsigned short)(u.x >> 16));
        a2 += bf2f((unsigned short)(u.y & 0xffff));
        a3 += bf2f((unsigned short)(u.y >> 16));
    }
    float dv = dinv[node];
    float4 bb = ((const float4*)b1)[l];
    float t0 = fmaxf(dv * a0 + bb.x, 0.0f);
    float t1 = fmaxf(dv * a1 + bb.y, 0.0f);
    float t2 = fmaxf(dv * a2 + bb.z, 0.0f);
    float t3 = fmaxf(dv * a3 + bb.w, 0.0f);
    u32x2 packed;
    packed[0] = (unsigned int)f2bf(t0) | ((unsigned int)f2bf(t1) << 16);
    packed[1] = (unsigned int)f2bf(t2) | ((unsigned int)f2bf(t3) << 16);
    __builtin_nontemporal_store(packed, (u32x2*)tbuf + (((unsigned)node << 5) + l));
}

// ---------------- GEMM2: tbuf[n,128]bf16 @ W2[128,16]f32 -> h2s bf16, *dinv ----------
// tbuf loads non-temporal (read-once; keep L2 for h2s gather table).
__global__ __launch_bounds__(256) void k_gemm2(const unsigned short* __restrict__ tbuf,
                                               const float* __restrict__ W2,
                                               const float* __restrict__ dinv,
                                               unsigned short* __restrict__ h2s, int n) {
    __shared__ float w2s[128 * 16];
    for (int i = threadIdx.x; i < 2048; i += 256) w2s[i] = W2[i];
    __syncthreads();
    int gid = blockIdx.x * 256 + threadIdx.x;
    int node = gid >> 4;
    int o = gid & 15;
    if (node >= n) return;
    const u32x4* tv = (const u32x4*)(tbuf + (size_t)node * 128);  // 16 x 16B
    float acc = 0.0f;
#pragma unroll
    for (int i = 0; i < 16; ++i) {
        u32x4 u = __builtin_nontemporal_load(tv + i);
        int k = i * 8;
        acc += __uint_as_float(u[0] << 16) * w2s[(k + 0) * 16 + o];
        acc += __uint_as_float(u[0] & 0xffff0000u) * w2s[(k + 1) * 16 + o];
        acc += __uint_as_float(u[1] << 16) * w2s[(k + 2) * 16 + o];
        acc += __uint_as_float(u[1] & 0xffff0000u) * w2s[(k + 3) * 16 + o];
        acc += __uint_as_float(u[2] << 16) * w2s[(k + 4) * 16 + o];
        acc += __uint_as_float(u[2] & 0xffff0000u) * w2s[(k + 5) * 16 + o];
        acc += __uint_as_float(u[3] << 16) * w2s[(k + 6) * 16 + o];
        acc += __uint_as_float(u[3] & 0xffff0000u) * w2s[(k + 7) * 16 + o];
    }
    h2s[(size_t)node * 16 + o] = f2bf(acc * dinv[node]);
}

// ---------------- agg2: 4 lanes/node, per-group divergent loop, 8-deep --------------
// h2s table is 3.2 MB (fits per-XCD L2): gathers are L2 hits. Each 4-lane
// group iterates its own degree (exec-masked), 8 gathers in flight. nt out.
__global__ __launch_bounds__(256) void k_agg2(const unsigned short* __restrict__ h2s,
                                              const int* __restrict__ rp,
                                              const int* __restrict__ csr,
                                              const float* __restrict__ dinv,
                                              const float* __restrict__ b2,
                                              float* __restrict__ out, int n) {
    int wid = (blockIdx.x * 256 + threadIdx.x) >> 6;
    int lane = threadIdx.x & 63;
    int slot = lane >> 2;
    int q = lane & 3;
    int node = wid * 16 + slot;
    if (node >= n) return;
    uint2 us = *(const uint2*)(h2s + ((unsigned)node << 4) + q * 4);
    float a0 = bf2f((unsigned short)(us.x & 0xffff));
    float a1 = bf2f((unsigned short)(us.x >> 16));
    float a2 = bf2f((unsigned short)(us.y & 0xffff));
    float a3 = bf2f((unsigned short)(us.y >> 16));
    int e = rp[node];
    const int end = rp[node + 1];
    for (; e + 8 <= end; e += 8) {
        int s0 = csr[e + 0], s1 = csr[e + 1], s2 = csr[e + 2], s3 = csr[e + 3];
        int s4 = csr[e + 4], s5 = csr[e + 5], s6 = csr[e + 6], s7 = csr[e + 7];
        uint2 u0 = *(const uint2*)(h2s + ((unsigned)s0 << 4) + q * 4);
        uint2 u1 = *(const uint2*)(h2s + ((unsigned)s1 << 4) + q * 4);
        uint2 u2 = *(const uint2*)(h2s + ((unsigned)s2 << 4) + q * 4);
        uint2 u3 = *(const uint2*)(h2s + ((unsigned)s3 << 4) + q * 4);
        uint2 u4 = *(const uint2*)(h2s + ((unsigned)s4 << 4) + q * 4);
        uint2 u5 = *(const uint2*)(h2s + ((unsigned)s5 << 4) + q * 4);
        uint2 u6 = *(const uint2*)(h2s + ((unsigned)s6 << 4) + q * 4);
        uint2 u7 = *(const uint2*)(h2s + ((unsigned)s7 << 4) + q * 4);
        a0 += (bf2f((unsigned short)(u0.x & 0xffff)) + bf2f((unsigned short)(u1.x & 0xffff))) +
              (bf2f((unsigned short)(u2.x & 0xffff)) + bf2f((unsigned short)(u3.x & 0xffff))) +
              (bf2f((unsigned short)(u4.x & 0xffff)) + bf2f((unsigned short)(u5.x & 0xffff))) +
              (bf2f((unsigned short)(u6.x & 0xffff)) + bf2f((unsigned short)(u7.x & 0xffff)));
        a1 += (bf2f((unsigned short)(u0.x >> 16)) + bf2f((unsigned short)(u1.x >> 16))) +
              (bf2f((unsigned short)(u2.x >> 16)) + bf2f((unsigned short)(u3.x >> 16))) +
              (bf2f((unsigned short)(u4.x >> 16)) + bf2f((unsigned short)(u5.x >> 16))) +
              (bf2f((unsigned short)(u6.x >> 16)) + bf2f((unsigned short)(u7.x >> 16)));
        a2 += (bf2f((unsigned short)(u0.y & 0xffff)) + bf2f((unsigned short)(u1.y & 0xffff))) +
              (bf2f((unsigned short)(u2.y & 0xffff)) + bf2f((unsigned short)(u3.y & 0xffff))) +
              (bf2f((unsigned short)(u4.y & 0xffff)) + bf2f((unsigned short)(u5.y & 0xffff))) +
              (bf2f((unsigned short)(u6.y & 0xffff)) + bf2f((unsigned short)(u7.y & 0xffff)));
        a3 += (bf2f((unsigned short)(u0.y >> 16)) + bf2f((unsigned short)(u1.y >> 16))) +
              (bf2f((unsigned short)(u2.y >> 16)) + bf2f((unsigned short)(u3.y >> 16))) +
              (bf2f((unsigned short)(u4.y >> 16)) + bf2f((unsigned short)(u5.y >> 16))) +
              (bf2f((unsigned short)(u6.y >> 16)) + bf2f((unsigned short)(u7.y >> 16)));
    }
    for (; e + 4 <= end; e += 4) {
        int s0 = csr[e + 0], s1 = csr[e + 1], s2 = csr[e + 2], s3 = csr[e + 3];
        uint2 u0 = *(const uint2*)(h2s + ((unsigned)s0 << 4) + q * 4);
        uint2 u1 = *(const uint2*)(h2s + ((unsigned)s1 << 4) + q * 4);
        uint2 u2 = *(const uint2*)(h2s + ((unsigned)s2 << 4) + q * 4);
        uint2 u3 = *(const uint2*)(h2s + ((unsigned)s3 << 4) + q * 4);
        a0 += (bf2f((unsigned short)(u0.x & 0xffff)) + bf2f((unsigned short)(u1.x & 0xffff))) +
              (bf2f((unsigned short)(u2.x & 0xffff)) + bf2f((unsigned short)(u3.x & 0xffff)));
        a1 += (bf2f((unsigned short)(u0.x >> 16)) + bf2f((unsigned short)(u1.x >> 16))) +
              (bf2f((unsigned short)(u2.x >> 16)) + bf2f((unsigned short)(u3.x >> 16)));
        a2 += (bf2f((unsigned short)(u0.y & 0xffff)) + bf2f((unsigned short)(u1.y & 0xffff))) +
              (bf2f((unsigned short)(u2.y & 0xffff)) + bf2f((unsigned short)(u3.y & 0xffff)));
        a3 += (bf2f((unsigned short)(u0.y >> 16)) + bf2f((unsigned short)(u1.y >> 16))) +
              (bf2f((unsigned short)(u2.y >> 16)) + bf2f((unsigned short)(u3.y >> 16)));
    }
    for (; e < end; ++e) {
        int s = csr[e];
        uint2 u = *(const uint2*)(h2s + ((unsigned)s << 4) + q * 4);
        a0 += bf2f((unsigned short)(u.x & 0xffff));
        a1 += bf2f((unsigned short)(u.x >> 16));
        a2 += bf2f((unsigned short)(u.y & 0xffff));
        a3 += bf2f((unsigned short)(u.y >> 16));
    }
    float dv = dinv[node];
    float4 bb = *(const float4*)(b2 + q * 4);
    f32x4 o4;
    o4[0] = dv * a0 + bb.x;
    o4[1] = dv * a1 + bb.y;
    o4[2] = dv * a2 + bb.z;
    o4[3] = dv * a3 + bb.w;
    __builtin_nontemporal_store(o4, (f32x4*)(out + ((unsigned)node << 4) + q * 4));
}

extern "C" void kernel_launch(void* const* d_in, const int* in_sizes, int n_in,
                              void* d_out, int out_size, void* d_ws, size_t ws_size,
                              hipStream_t stream) {
    const float* X  = (const float*)d_in[0];
    const int*   ei = (const int*)d_in[1];
    const float* W1 = (const float*)d_in[2];
    const float* b1 = (const float*)d_in[3];
    const float* W2 = (const float*)d_in[4];
    const float* b2 = (const float*)d_in[5];
    float* out = (float*)d_out;

    const int n = in_sizes[0] / N_FEAT_IN;   // 100000
    const int E = in_sizes[1] / 2;           // 1600000
    const int* src = ei;
    const int* dst = ei + E;

    char* ws = (char*)d_ws;
    size_t off = 0;
    auto alloc = [&](size_t bytes) -> char* {
        char* p = ws + off;
        off = (off + bytes + 255) & ~(size_t)255;
        return p;
    };
    float*          dinv    = (float*)alloc((size_t)n * 4);
    int*            row_ptr = (int*)alloc((size_t)(n + 1) * 4);
    int*            bbc     = (int*)alloc((size_t)NBUCK * NBINBLK * 4);  // 1 MB
    int*            btot    = (int*)alloc(NBUCK * 4);
    int*            bbase   = (int*)alloc((NBUCK + 1) * 4);
    int*            csr     = (int*)alloc((size_t)E * 4);
    int*            ebuf    = (int*)alloc((size_t)E * 4);                // 6.4 MB packed
    unsigned short* W1t     = (unsigned short*)alloc(128 * 256 * 2);     // 64 KB packed
    unsigned short* h1s     = (unsigned short*)alloc((size_t)n * 128 * 2);
    unsigned short* tbuf    = (unsigned short*)alloc((size_t)n * 128 * 2);
    unsigned short* h2s     = (unsigned short*)alloc((size_t)n * 16 * 2);
    (void)ws_size;

    const int NBK = (n + 127) / 128;         // 782 used buckets
    const int chunk = (E + NBINBLK - 1) / NBINBLK;

    k_bhist<<<NBINBLK, 256, 0, stream>>>(dst, bbc, E, chunk);
    k_bexscan<<<NBUCK, 256, 0, stream>>>(bbc, btot);
    k_bscan<<<1, NBUCK, 0, stream>>>(btot, bbase);
    k_bin2<<<NBINBLK, 256, 0, stream>>>(src, dst, bbc, bbase, ebuf, E, chunk);
    k_sortb<<<NBK, 256, 0, stream>>>(ebuf, bbase, row_ptr, dinv, csr, n, E);

    k_prep<<<128, 256, 0, stream>>>(W1, W1t);
    k_gemm1<<<(n + 63) / 64, 256, 0, stream>>>(X, W1t, dinv, h1s, n);
    k_agg1<<<(n / 2 + 3) / 4, 256, 0, stream>>>(h1s, row_ptr, csr, dinv, b1, tbuf, n);
    k_gemm2<<<((size_t)n * 16 + 255) / 256, 256, 0, stream>>>(tbuf, W2, dinv, h2s, n);
    k_agg2<<<(n + 63) / 64, 256, 0, stream>>>(h2s, row_ptr, csr, dinv, b2, out, n);
}

// Round 10
// 315.706 us; speedup vs baseline: 1.0689x; 1.0689x over previous
//
#include <hip/hip_runtime.h>
#include <hip/hip_bf16.h>

// SocialGNN: 2-layer GCN, N=100000 nodes, E=1600000 edges (+ self loops),
// feat 256 -> 128 (relu) -> 16.
//
// R19 = R16 + gemm2 fused into agg1 as a BLOCK-LEVEL LDS epilogue (k_agg1g).
// R17 proved eliminating gemm2+tbuf is worth ~27us net, but its REGISTER
// epilogue (W2 slice +40 VGPR, 92-op shfl tree) collapsed occupancy 70->38%.
// R19 keeps the gather loop byte-identical (VGPR ~24): t goes bf16-packed to
// LDS (2KB) instead of global tbuf; W2 transposed in LDS (8.4KB, stride-132
// pad); one barrier; threads 0..127 compute (node,o) dots via LDS-broadcast
// and write 256 contiguous bytes of h2s per block. Same bf16 bits, same
// ascending-k accumulation order as R16's gemm2 -> numerically identical.
// R18's src-half split REVERTED: FETCH unchanged (falsifier fired) -- waves
// don't sweep in lockstep; agg1 gather is at its random-access HBM roofline.
// History: R2 -- never funnel E atomics into <1K addresses. R4 -- bf16
// intermediates halve gather traffic. R7 -- per-wave-redundant MFMA operand
// streams = 2x regression. R9 -- resident-B LDS gemm1. R10-R13 -- XCD
// feature-chunking abandoned (node reordering poisons store coalescing).
// R14 -- 8-deep agg1 61us. R16 -- gemm1 half-K LDS, agg2 divergent 8-deep,
// nt hints: 335us (best). R17 -- register-epilogue fusion 90us (occupancy).

typedef __attribute__((ext_vector_type(8))) short short8;
typedef __attribute__((ext_vector_type(4))) float f32x4;
typedef __attribute__((ext_vector_type(2))) unsigned int u32x2;
typedef __attribute__((ext_vector_type(4))) unsigned int u32x4;

__device__ inline unsigned short f2bf(float f) {
    __hip_bfloat16 h = __float2bfloat16(f);
    return *(unsigned short*)&h;
}
__device__ inline float bf2f(unsigned short u) {
    unsigned int v = ((unsigned int)u) << 16;
    return *(float*)&v;
}

#define N_FEAT_IN 256
#define NBUCK 1024     // dst>>7; used buckets = ceil(n/128) = 782
#define NBINBLK 256    // partition blocks; bbc is [NBUCK][NBINBLK]

// ---------------- partition pass 1: per-(block,bucket) LDS histogram ----------------
__global__ __launch_bounds__(256) void k_bhist(const int* __restrict__ dst,
                                               int* __restrict__ bbc, int E, int chunk) {
    __shared__ int lcnt[NBUCK];
    for (int i = threadIdx.x; i < NBUCK; i += 256) lcnt[i] = 0;
    __syncthreads();
    int start = blockIdx.x * chunk;
    int end = min(start + chunk, E);
    for (int e = start + threadIdx.x; e < end; e += 256)
        atomicAdd(&lcnt[dst[e] >> 7], 1);
    __syncthreads();
    for (int i = threadIdx.x; i < NBUCK; i += 256)
        bbc[i * NBINBLK + blockIdx.x] = lcnt[i];
}

// ---- partition pass 2: per-bucket local exclusive scan across blocks + totals ----
__global__ __launch_bounds__(256) void k_bexscan(int* __restrict__ bbc,
                                                 int* __restrict__ btot) {
    __shared__ int ts[NBINBLK];
    int bucket = blockIdx.x;
    int t = threadIdx.x;
    int v = bbc[bucket * NBINBLK + t];
    ts[t] = v; __syncthreads();
    for (int off = 1; off < NBINBLK; off <<= 1) {
        int x = (t >= off) ? ts[t - off] : 0;
        __syncthreads();
        ts[t] += x;
        __syncthreads();
    }
    bbc[bucket * NBINBLK + t] = ts[t] - v;   // local exclusive (no base yet)
    if (t == NBINBLK - 1) btot[bucket] = ts[t];
}

// ---------------- bucket-total exclusive scan -> bucket bases ----------------
__global__ __launch_bounds__(1024) void k_bscan(const int* __restrict__ btot,
                                                int* __restrict__ bbase) {
    __shared__ int ts[NBUCK];
    int t = threadIdx.x;
    int v = btot[t];
    ts[t] = v; __syncthreads();
    for (int off = 1; off < NBUCK; off <<= 1) {
        int x = (t >= off) ? ts[t - off] : 0;
        __syncthreads();
        ts[t] += x;
        __syncthreads();
    }
    bbase[t] = ts[t] - v;  // exclusive
}

// ---------------- partition pass 3: binned write (24-bit packed) ----------------
// packed edge: bits 0-16 src (n<2^17), bits 17-23 dst&127.
__global__ __launch_bounds__(256) void k_bin2(const int* __restrict__ src,
                                              const int* __restrict__ dst,
                                              const int* __restrict__ bbc,
                                              const int* __restrict__ bbase,
                                              int* __restrict__ ebuf, int E, int chunk) {
    __shared__ int lcur[NBUCK];
    for (int i = threadIdx.x; i < NBUCK; i += 256)
        lcur[i] = bbc[i * NBINBLK + blockIdx.x] + bbase[i];
    __syncthreads();
    int start = blockIdx.x * chunk;
    int end = min(start + chunk, E);
    for (int e = start + threadIdx.x; e < end; e += 256) {
        int s = src[e], d = dst[e];
        int pos = atomicAdd(&lcur[d >> 7], 1);  // LDS atomic
        ebuf[pos] = s | ((d & 127) << 17);
    }
}

// ---- per-bucket counting sort: ebuf window -> csr; also row_ptr, dinv ----
__global__ __launch_bounds__(256) void k_sortb(const int* __restrict__ ebuf,
                                               const int* __restrict__ bbase,
                                               int* __restrict__ row_ptr,
                                               float* __restrict__ dinv,
                                               int* __restrict__ csr, int n, int E) {
    __shared__ int lcnt[128];
    __shared__ int lcur[128];
    int b = blockIdx.x;
    int node0 = b << 7;
    int nodes = min(128, n - node0);
    int t = threadIdx.x;
    int s_start = bbase[b];
    int s_end = bbase[b + 1];
    if (t < 128) lcnt[t] = 0;
    __syncthreads();
    for (int e = s_start + t; e < s_end; e += 256)
        atomicAdd(&lcnt[(ebuf[e] >> 17) & 127], 1);
    __syncthreads();
    int deg = (t < 128) ? lcnt[t] : 0;
    if (t < 128) lcur[t] = deg;
    __syncthreads();
    for (int off = 1; off < 128; off <<= 1) {
        int x = 0;
        if (t < 128 && t >= off) x = lcur[t - off];
        __syncthreads();
        if (t < 128) lcur[t] += x;
        __syncthreads();
    }
    if (t < 128) {
        int excl = s_start + lcur[t] - deg;
        if (t < nodes) {
            row_ptr[node0 + t] = excl;
            dinv[node0 + t] = rsqrtf((float)deg + 1.0f);  // +1 self-loop
        }
        lcur[t] = excl;  // write cursor
    }
    if (b == 0 && t == 0) row_ptr[n] = E;
    __syncthreads();
    for (int e = s_start + t; e < s_end; e += 256) {
        int p = ebuf[e];
        int pos = atomicAdd(&lcur[(p >> 17) & 127], 1);  // LDS atomic
        csr[pos] = p & 0x1FFFF;
    }
}

// ------ W1 [256][128] f32 -> W1t packed [kq 0..31][n 0..127][j 0..7] bf16 ------
// element (n, k=kq*8+j) lives at W1t[kq*1024 + n*8 + j].
__global__ void k_prep(const float* __restrict__ W1, unsigned short* __restrict__ W1t) {
    int nn = blockIdx.x;          // 0..127
    int k = threadIdx.x;          // 0..255
    int kq = k >> 3, j = k & 7;
    W1t[kq * 1024 + nn * 8 + j] = f2bf(W1[k * 128 + nn]);
}

// ---------------- GEMM1 (MFMA, half-K resident-B): X[M,256]f32 @ W1 -> h1s ----------
// 32 KB LDS (half of W1 at a time), 2 compute phases, 3 barriers/block ->
// 5 blocks/CU. X loads non-temporal (read-once stream).
__global__ __launch_bounds__(256) void k_gemm1(const float* __restrict__ X,
                                               const unsigned short* __restrict__ W1t,
                                               const float* __restrict__ dinv,
                                               unsigned short* __restrict__ h1s, int M) {
    __shared__ unsigned short Bs[16384];   // 32 KB, [kq' 0..15][n][8]
    const int tid = threadIdx.x;
    const int wv = tid >> 6;
    const int lane = tid & 63;
    const int hq = lane >> 4;       // quad 0..3
    const int l15 = lane & 15;
    const int block_row = blockIdx.x * 64;

    int arow = block_row + wv * 16 + l15;
    if (arow >= M) arow = M - 1;                       // clamp; stores masked
    const float* xp = X + (size_t)arow * 256 + hq * 8;

    f32x4 acc[8];
#pragma unroll
    for (int c = 0; c < 8; ++c) acc[c] = (f32x4){0.f, 0.f, 0.f, 0.f};

#pragma unroll
    for (int ph = 0; ph < 2; ++ph) {
        if (ph) __syncthreads();           // all reads of phase 0 done
#pragma unroll
        for (int i = 0; i < 8; ++i)
            ((u32x4*)Bs)[tid + i * 256] = ((const u32x4*)W1t)[ph * 2048 + tid + i * 256];
        __syncthreads();
#pragma unroll
        for (int ks4 = 0; ks4 < 4; ++ks4) {            // ks = ph*4 + ks4
            const int ks = ph * 4 + ks4;
            f32x4 a0 = __builtin_nontemporal_load((const f32x4*)(xp + 32 * ks));
            f32x4 a1 = __builtin_nontemporal_load((const f32x4*)(xp + 32 * ks + 4));
            short8 a;
            a[0] = (short)f2bf(a0[0]); a[1] = (short)f2bf(a0[1]);
            a[2] = (short)f2bf(a0[2]); a[3] = (short)f2bf(a0[3]);
            a[4] = (short)f2bf(a1[0]); a[5] = (short)f2bf(a1[1]);
            a[6] = (short)f2bf(a1[2]); a[7] = (short)f2bf(a1[3]);
            const unsigned short* bp = Bs + (ks4 * 4 + hq) * 1024 + l15 * 8;
#pragma unroll
            for (int c = 0; c < 8; ++c) {
                short8 b = *(const short8*)(bp + c * 128);
                acc[c] = __builtin_amdgcn_mfma_f32_16x16x32_bf16(a, b, acc[c], 0, 0, 0);
            }
        }
    }
    // D: row = 16wv + hq*4 + r, col = c*16 + l15
#pragma unroll
    for (int r = 0; r < 4; ++r) {
        int row = block_row + 16 * wv + hq * 4 + r;
        if (row < M) {
            float dv = dinv[row];
#pragma unroll
            for (int c = 0; c < 8; ++c) {
                int col = c * 16 + l15;
                h1s[(size_t)row * 128 + col] = f2bf(acc[c][r] * dv);
            }
        }
    }
}

// ------- agg1 + fused 128->16 projection (block-level LDS epilogue) ---------------
// Gather loop byte-identical to R16's k_agg1 (2 nodes/wave, 8-deep, 24 VGPR).
// t (relu'd, bf16-packed -- same bits as R16's tbuf) goes to LDS sT[8][64];
// W2 transposed in LDS w2t[16][132] (pad kills write conflicts; rows 16B
// aligned for b128 reads). After one barrier, threads 0..127 (nl=t>>4,o=t&15)
// accumulate 128 terms in R16-gemm2's exact ascending-k order and write h2s
// (256 contiguous B per block). tbuf + k_gemm2 + 1 launch eliminated.
__global__ __launch_bounds__(256) void k_agg1g(const unsigned short* __restrict__ h1s,
                                               const int* __restrict__ rp,
                                               const int* __restrict__ csr,
                                               const float* __restrict__ dinv,
                                               const float* __restrict__ b1,
                                               const float* __restrict__ W2,
                                               unsigned short* __restrict__ h2s, int n) {
    __shared__ float w2t[16][132];          // [o][k], stride 132 (528B, 16B-aligned)
    __shared__ unsigned int sT[8][64];      // 8 nodes x 64 packed-bf16-pairs
    const int tid = threadIdx.x;

    // stage W2 transposed: i = k*16+o -> w2t[o][k]
#pragma unroll
    for (int j = 0; j < 8; ++j) {
        int i = tid + j * 256;              // 0..2047
        w2t[i & 15][i >> 4] = W2[i];
    }

    int pr = (blockIdx.x * 256 + tid) >> 6;  // wave id = node pair
    int lane = tid & 63;
    int half = lane >> 5;
    int l = lane & 31;
    int node = pr * 2 + half;
    const int nl = tid >> 5;                 // node-local 0..7
    const int base = blockIdx.x * 8;

    if (node < n) {
        const uint2* hv = (const uint2*)h1s;  // 32 uint2 per 128-feat row
        uint2 us = hv[((unsigned)node << 5) + l];  // self (already *dinv)
        float a0 = bf2f((unsigned short)(us.x & 0xffff));
        float a1 = bf2f((unsigned short)(us.x >> 16));
        float a2 = bf2f((unsigned short)(us.y & 0xffff));
        float a3 = bf2f((unsigned short)(us.y >> 16));
        int start = rp[node], end = rp[node + 1];
        int e = start;
        for (; e + 8 <= end; e += 8) {
            uint2 u0 = hv[((unsigned)csr[e + 0] << 5) + l];
            uint2 u1 = hv[((unsigned)csr[e + 1] << 5) + l];
            uint2 u2 = hv[((unsigned)csr[e + 2] << 5) + l];
            uint2 u3 = hv[((unsigned)csr[e + 3] << 5) + l];
            uint2 u4 = hv[((unsigned)csr[e + 4] << 5) + l];
            uint2 u5 = hv[((unsigned)csr[e + 5] << 5) + l];
            uint2 u6 = hv[((unsigned)csr[e + 6] << 5) + l];
            uint2 u7 = hv[((unsigned)csr[e + 7] << 5) + l];
            a0 += (bf2f((unsigned short)(u0.x & 0xffff)) + bf2f((unsigned short)(u1.x & 0xffff))) +
                  (bf2f((unsigned short)(u2.x & 0xffff)) + bf2f((unsigned short)(u3.x & 0xffff))) +
                  (bf2f((unsigned short)(u4.x & 0xffff)) + bf2f((unsigned short)(u5.x & 0xffff))) +
                  (bf2f((unsigned short)(u6.x & 0xffff)) + bf2f((unsigned short)(u7.x & 0xffff)));
            a1 += (bf2f((unsigned short)(u0.x >> 16)) + bf2f((unsigned short)(u1.x >> 16))) +
                  (bf2f((unsigned short)(u2.x >> 16)) + bf2f((unsigned short)(u3.x >> 16))) +
                  (bf2f((unsigned short)(u4.x >> 16)) + bf2f((unsigned short)(u5.x >> 16))) +
                  (bf2f((unsigned short)(u6.x >> 16)) + bf2f((unsigned short)(u7.x >> 16)));
            a2 += (bf2f((unsigned short)(u0.y & 0xffff)) + bf2f((unsigned short)(u1.y & 0xffff))) +
                  (bf2f((unsigned short)(u2.y & 0xffff)) + bf2f((unsigned short)(u3.y & 0xffff))) +
                  (bf2f((unsigned short)(u4.y & 0xffff)) + bf2f((unsigned short)(u5.y & 0xffff))) +
                  (bf2f((unsigned short)(u6.y & 0xffff)) + bf2f((unsigned short)(u7.y & 0xffff)));
            a3 += (bf2f((unsigned short)(u0.y >> 16)) + bf2f((unsigned short)(u1.y >> 16))) +
                  (bf2f((unsigned short)(u2.y >> 16)) + bf2f((unsigned short)(u3.y >> 16))) +
                  (bf2f((unsigned short)(u4.y >> 16)) + bf2f((unsigned short)(u5.y >> 16))) +
                  (bf2f((unsigned short)(u6.y >> 16)) + bf2f((unsigned short)(u7.y >> 16)));
        }
        for (; e + 4 <= end; e += 4) {
            uint2 u0 = hv[((unsigned)csr[e + 0] << 5) + l];
            uint2 u1 = hv[((unsigned)csr[e + 1] << 5) + l];
            uint2 u2 = hv[((unsigned)csr[e + 2] << 5) + l];
            uint2 u3 = hv[((unsigned)csr[e + 3] << 5) + l];
            a0 += (bf2f((unsigned short)(u0.x & 0xffff)) + bf2f((unsigned short)(u1.x & 0xffff))) +
                  (bf2f((unsigned short)(u2.x & 0xffff)) + bf2f((unsigned short)(u3.x & 0xffff)));
            a1 += (bf2f((unsigned short)(u0.x >> 16)) + bf2f((unsigned short)(u1.x >> 16))) +
                  (bf2f((unsigned short)(u2.x >> 16)) + bf2f((unsigned short)(u3.x >> 16)));
            a2 += (bf2f((unsigned short)(u0.y & 0xffff)) + bf2f((unsigned short)(u1.y & 0xffff))) +
                  (bf2f((unsigned short)(u2.y & 0xffff)) + bf2f((unsigned short)(u3.y & 0xffff)));
            a3 += (bf2f((unsigned short)(u0.y >> 16)) + bf2f((unsigned short)(u1.y >> 16))) +
                  (bf2f((unsigned short)(u2.y >> 16)) + bf2f((unsigned short)(u3.y >> 16)));
        }
        for (; e < end; ++e) {
            uint2 u = hv[((unsigned)csr[e] << 5) + l];
            a0 += bf2f((unsigned short)(u.x & 0xffff));
            a1 += bf2f((unsigned short)(u.x >> 16));
            a2 += bf2f((unsigned short)(u.y & 0xffff));
            a3 += bf2f((unsigned short)(u.y >> 16));
        }
        float dv = dinv[node];
        float4 bb = ((const float4*)b1)[l];
        float t0 = fmaxf(dv * a0 + bb.x, 0.0f);
        float t1 = fmaxf(dv * a1 + bb.y, 0.0f);
        float t2 = fmaxf(dv * a2 + bb.z, 0.0f);
        float t3 = fmaxf(dv * a3 + bb.w, 0.0f);
        sT[nl][2 * l]     = (unsigned int)f2bf(t0) | ((unsigned int)f2bf(t1) << 16);
        sT[nl][2 * l + 1] = (unsigned int)f2bf(t2) | ((unsigned int)f2bf(t3) << 16);
    }
    __syncthreads();
    if (tid < 128) {
        int nl2 = tid >> 4, o = tid & 15;
        int node2 = base + nl2;
        if (node2 < n) {
            const unsigned int* trow = sT[nl2];
            const float* wrow = w2t[o];
            float acc = 0.0f;
#pragma unroll
            for (int j = 0; j < 64; ++j) {
                unsigned int u = trow[j];
                acc += __uint_as_float(u << 16) * wrow[2 * j];
                acc += __uint_as_float(u & 0xffff0000u) * wrow[2 * j + 1];
            }
            h2s[(size_t)node2 * 16 + o] = f2bf(acc * dinv[node2]);
        }
    }
}

// ---------------- agg2: 4 lanes/node, per-group divergent loop, 8-deep --------------
// h2s table is 3.2 MB (fits per-XCD L2): gathers are L2 hits. Each 4-lane
// group iterates its own degree (exec-masked), 8 gathers in flight. nt out.
__global__ __launch_bounds__(256) void k_agg2(const unsigned short* __restrict__ h2s,
                                              const int* __restrict__ rp,
                                              const int* __restrict__ csr,
                                              const float* __restrict__ dinv,
                                              const float* __restrict__ b2,
                                              float* __restrict__ out, int n) {
    int wid = (blockIdx.x * 256 + threadIdx.x) >> 6;
    int lane = threadIdx.x & 63;
    int slot = lane >> 2;
    int q = lane & 3;
    int node = wid * 16 + slot;
    if (node >= n) return;
    uint2 us = *(const uint2*)(h2s + ((unsigned)node << 4) + q * 4);
    float a0 = bf2f((unsigned short)(us.x & 0xffff));
    float a1 = bf2f((unsigned short)(us.x >> 16));
    float a2 = bf2f((unsigned short)(us.y & 0xffff));
    float a3 = bf2f((unsigned short)(us.y >> 16));
    int e = rp[node];
    const int end = rp[node + 1];
    for (; e + 8 <= end; e += 8) {
        int s0 = csr[e + 0], s1 = csr[e + 1], s2 = csr[e + 2], s3 = csr[e + 3];
        int s4 = csr[e + 4], s5 = csr[e + 5], s6 = csr[e + 6], s7 = csr[e + 7];
        uint2 u0 = *(const uint2*)(h2s + ((unsigned)s0 << 4) + q * 4);
        uint2 u1 = *(const uint2*)(h2s + ((unsigned)s1 << 4) + q * 4);
        uint2 u2 = *(const uint2*)(h2s + ((unsigned)s2 << 4) + q * 4);
        uint2 u3 = *(const uint2*)(h2s + ((unsigned)s3 << 4) + q * 4);
        uint2 u4 = *(const uint2*)(h2s + ((unsigned)s4 << 4) + q * 4);
        uint2 u5 = *(const uint2*)(h2s + ((unsigned)s5 << 4) + q * 4);
        uint2 u6 = *(const uint2*)(h2s + ((unsigned)s6 << 4) + q * 4);
        uint2 u7 = *(const uint2*)(h2s + ((unsigned)s7 << 4) + q * 4);
        a0 += (bf2f((unsigned short)(u0.x & 0xffff)) + bf2f((unsigned short)(u1.x & 0xffff))) +
              (bf2f((unsigned short)(u2.x & 0xffff)) + bf2f((unsigned short)(u3.x & 0xffff))) +
              (bf2f((unsigned short)(u4.x & 0xffff)) + bf2f((unsigned short)(u5.x & 0xffff))) +
              (bf2f((unsigned short)(u6.x & 0xffff)) + bf2f((unsigned short)(u7.x & 0xffff)));
        a1 += (bf2f((unsigned short)(u0.x >> 16)) + bf2f((unsigned short)(u1.x >> 16))) +
              (bf2f((unsigned short)(u2.x >> 16)) + bf2f((unsigned short)(u3.x >> 16))) +
              (bf2f((unsigned short)(u4.x >> 16)) + bf2f((unsigned short)(u5.x >> 16))) +
              (bf2f((unsigned short)(u6.x >> 16)) + bf2f((unsigned short)(u7.x >> 16)));
        a2 += (bf2f((unsigned short)(u0.y & 0xffff)) + bf2f((unsigned short)(u1.y & 0xffff))) +
              (bf2f((unsigned short)(u2.y & 0xffff)) + bf2f((unsigned short)(u3.y & 0xffff))) +
              (bf2f((unsigned short)(u4.y & 0xffff)) + bf2f((unsigned short)(u5.y & 0xffff))) +
              (bf2f((unsigned short)(u6.y & 0xffff)) + bf2f((unsigned short)(u7.y & 0xffff)));
        a3 += (bf2f((unsigned short)(u0.y >> 16)) + bf2f((unsigned short)(u1.y >> 16))) +
              (bf2f((unsigned short)(u2.y >> 16)) + bf2f((unsigned short)(u3.y >> 16))) +
              (bf2f((unsigned short)(u4.y >> 16)) + bf2f((unsigned short)(u5.y >> 16))) +
              (bf2f((unsigned short)(u6.y >> 16)) + bf2f((unsigned short)(u7.y >> 16)));
    }
    for (; e + 4 <= end; e += 4) {
        int s0 = csr[e + 0], s1 = csr[e + 1], s2 = csr[e + 2], s3 = csr[e + 3];
        uint2 u0 = *(const uint2*)(h2s + ((unsigned)s0 << 4) + q * 4);
        uint2 u1 = *(const uint2*)(h2s + ((unsigned)s1 << 4) + q * 4);
        uint2 u2 = *(const uint2*)(h2s + ((unsigned)s2 << 4) + q * 4);
        uint2 u3 = *(const uint2*)(h2s + ((unsigned)s3 << 4) + q * 4);
        a0 += (bf2f((unsigned short)(u0.x & 0xffff)) + bf2f((unsigned short)(u1.x & 0xffff))) +
              (bf2f((unsigned short)(u2.x & 0xffff)) + bf2f((unsigned short)(u3.x & 0xffff)));
        a1 += (bf2f((unsigned short)(u0.x >> 16)) + bf2f((unsigned short)(u1.x >> 16))) +
              (bf2f((unsigned short)(u2.x >> 16)) + bf2f((unsigned short)(u3.x >> 16)));
        a2 += (bf2f((unsigned short)(u0.y & 0xffff)) + bf2f((unsigned short)(u1.y & 0xffff))) +
              (bf2f((unsigned short)(u2.y & 0xffff)) + bf2f((unsigned short)(u3.y & 0xffff)));
        a3 += (bf2f((unsigned short)(u0.y >> 16)) + bf2f((unsigned short)(u1.y >> 16))) +
              (bf2f((unsigned short)(u2.y >> 16)) + bf2f((unsigned short)(u3.y >> 16)));
    }
    for (; e < end; ++e) {
        int s = csr[e];
        uint2 u = *(const uint2*)(h2s + ((unsigned)s << 4) + q * 4);
        a0 += bf2f((unsigned short)(u.x & 0xffff));
        a1 += bf2f((unsigned short)(u.x >> 16));
        a2 += bf2f((unsigned short)(u.y & 0xffff));
        a3 += bf2f((unsigned short)(u.y >> 16));
    }
    float dv = dinv[node];
    float4 bb = *(const float4*)(b2 + q * 4);
    f32x4 o4;
    o4[0] = dv * a0 + bb.x;
    o4[1] = dv * a1 + bb.y;
    o4[2] = dv * a2 + bb.z;
    o4[3] = dv * a3 + bb.w;
    __builtin_nontemporal_store(o4, (f32x4*)(out + ((unsigned)node << 4) + q * 4));
}

extern "C" void kernel_launch(void* const* d_in, const int* in_sizes, int n_in,
                              void* d_out, int out_size, void* d_ws, size_t ws_size,
                              hipStream_t stream) {
    const float* X  = (const float*)d_in[0];
    const int*   ei = (const int*)d_in[1];
    const float* W1 = (const float*)d_in[2];
    const float* b1 = (const float*)d_in[3];
    const float* W2 = (const float*)d_in[4];
    const float* b2 = (const float*)d_in[5];
    float* out = (float*)d_out;

    const int n = in_sizes[0] / N_FEAT_IN;   // 100000
    const int E = in_sizes[1] / 2;           // 1600000
    const int* src = ei;
    const int* dst = ei + E;

    char* ws = (char*)d_ws;
    size_t off = 0;
    auto alloc = [&](size_t bytes) -> char* {
        char* p = ws + off;
        off = (off + bytes + 255) & ~(size_t)255;
        return p;
    };
    float*          dinv    = (float*)alloc((size_t)n * 4);
    int*            row_ptr = (int*)alloc((size_t)(n + 1) * 4);
    int*            bbc     = (int*)alloc((size_t)NBUCK * NBINBLK * 4);  // 1 MB
    int*            btot    = (int*)alloc(NBUCK * 4);
    int*            bbase   = (int*)alloc((NBUCK + 1) * 4);
    int*            csr     = (int*)alloc((size_t)E * 4);
    int*            ebuf    = (int*)alloc((size_t)E * 4);                // 6.4 MB packed
    unsigned short* W1t     = (unsigned short*)alloc(128 * 256 * 2);     // 64 KB packed
    unsigned short* h1s     = (unsigned short*)alloc((size_t)n * 128 * 2);
    unsigned short* h2s     = (unsigned short*)alloc((size_t)n * 16 * 2);
    (void)ws_size;

    const int NBK = (n + 127) / 128;         // 782 used buckets
    const int chunk = (E + NBINBLK - 1) / NBINBLK;

    k_bhist<<<NBINBLK, 256, 0, stream>>>(dst, bbc, E, chunk);
    k_bexscan<<<NBUCK, 256, 0, stream>>>(bbc, btot);
    k_bscan<<<1, NBUCK, 0, stream>>>(btot, bbase);
    k_bin2<<<NBINBLK, 256, 0, stream>>>(src, dst, bbc, bbase, ebuf, E, chunk);
    k_sortb<<<NBK, 256, 0, stream>>>(ebuf, bbase, row_ptr, dinv, csr, n, E);

    k_prep<<<128, 256, 0, stream>>>(W1, W1t);
    k_gemm1<<<(n + 63) / 64, 256, 0, stream>>>(X, W1t, dinv, h1s, n);
    k_agg1g<<<(n + 7) / 8, 256, 0, stream>>>(h1s, row_ptr, csr, dinv, b1, W2, h2s, n);
    k_agg2<<<(n + 63) / 64, 256, 0, stream>>>(h2s, row_ptr, csr, dinv, b2, out, n);
}